// Round 1
// baseline (1626.286 us; speedup 1.0000x reference)
//
#include <hip/hip_runtime.h>

// GCNConv: out = A_hat @ (X @ W + b)
// X [16384,512] f32, A_hat [16384,16384] f32, W [512,256] f32, b [256] f32
// Strategy:
//   k1: H^T = (X@W + b)^T as bf16 [256][16384] into d_ws (MFMA 16x16x32 bf16)
//   k2: out = A_hat @ H, BM=128 BN=256(full), split-K=2, atomicAdd fp32 epilogue
//       A_hat converted f32->bf16 during LDS staging; LDS stride 40 (pad) = 2-way max conflicts

typedef short bf16x8 __attribute__((ext_vector_type(8)));
typedef float f32x4 __attribute__((ext_vector_type(4)));

__device__ __forceinline__ unsigned f2bf(float f) {
  unsigned u = __float_as_uint(f);
  unsigned r = 0x7fffu + ((u >> 16) & 1u);
  return (u + r) >> 16;  // bf16 bits (RNE) in low 16
}
__device__ __forceinline__ unsigned pack2(float lo, float hi) {
  return f2bf(lo) | (f2bf(hi) << 16);
}

// ---------------- Kernel 1: H^T[n][m] = sum_k X[m][k] W[k][n] + b[n], bf16 ----
__global__ __launch_bounds__(256, 2)
void gcn_proj(const float* __restrict__ X, const float* __restrict__ W,
              const float* __restrict__ bias, unsigned short* __restrict__ HT) {
  __shared__ unsigned short Xs[128 * 40];
  __shared__ unsigned short Ws[128 * 40];
  const int tid = threadIdx.x;
  const int bx = blockIdx.x;
  const int m0 = (bx & 127) * 128;
  const int n0 = (bx >> 7) * 128;
  const int lane = tid & 63;
  const int w = tid >> 6;
  const int wm = (w & 1) * 64;
  const int wn = (w >> 1) * 64;
  const int ln = lane & 15;
  const int q = lane >> 4;

  f32x4 acc[4][4];
#pragma unroll
  for (int i = 0; i < 4; ++i)
#pragma unroll
    for (int j = 0; j < 4; ++j) acc[i][j] = (f32x4)0.0f;

  const int xr = tid >> 1;          // 0..127 (X tile row)
  const int xh = (tid & 1) * 16;    // 0 or 16 (X tile col base)
  const int wk = tid >> 3;          // 0..31  (W tile k row)
  const int wng = (tid & 7) * 16;   // W tile n group

  for (int ks = 0; ks < 512; ks += 32) {
    const float* xp = X + (size_t)(m0 + xr) * 512 + ks + xh;
    float4 x0 = *(const float4*)(xp + 0);
    float4 x1 = *(const float4*)(xp + 4);
    float4 x2 = *(const float4*)(xp + 8);
    float4 x3 = *(const float4*)(xp + 12);
    const float* wp = W + (size_t)(ks + wk) * 256 + n0 + wng;
    float4 w0 = *(const float4*)(wp + 0);
    float4 w1 = *(const float4*)(wp + 4);
    float4 w2 = *(const float4*)(wp + 8);
    float4 w3 = *(const float4*)(wp + 12);
    __syncthreads();  // previous iteration's LDS reads complete
    unsigned* xd = (unsigned*)&Xs[xr * 40 + xh];
    xd[0] = pack2(x0.x, x0.y); xd[1] = pack2(x0.z, x0.w);
    xd[2] = pack2(x1.x, x1.y); xd[3] = pack2(x1.z, x1.w);
    xd[4] = pack2(x2.x, x2.y); xd[5] = pack2(x2.z, x2.w);
    xd[6] = pack2(x3.x, x3.y); xd[7] = pack2(x3.z, x3.w);
    const float wv[16] = {w0.x, w0.y, w0.z, w0.w, w1.x, w1.y, w1.z, w1.w,
                          w2.x, w2.y, w2.z, w2.w, w3.x, w3.y, w3.z, w3.w};
#pragma unroll
    for (int j = 0; j < 16; ++j)
      Ws[(wng + j) * 40 + wk] = (unsigned short)f2bf(wv[j]);  // transpose scatter
    __syncthreads();

    bf16x8 af[4], bfr[4];
#pragma unroll
    for (int i = 0; i < 4; ++i)
      af[i] = *(const bf16x8*)&Xs[(wm + i * 16 + ln) * 40 + q * 8];
#pragma unroll
    for (int j = 0; j < 4; ++j)
      bfr[j] = *(const bf16x8*)&Ws[(wn + j * 16 + ln) * 40 + q * 8];
#pragma unroll
    for (int i = 0; i < 4; ++i)
#pragma unroll
      for (int j = 0; j < 4; ++j)
        acc[i][j] = __builtin_amdgcn_mfma_f32_16x16x32_bf16(af[i], bfr[j], acc[i][j], 0, 0, 0);
  }

  // epilogue: write H^T[n][m] bf16; C/D layout: n(col)=lane&15, m(row)=q*4+reg
#pragma unroll
  for (int j = 0; j < 4; ++j) {
    const int n = n0 + wn + j * 16 + ln;
    const float bv = bias[n];
#pragma unroll
    for (int i = 0; i < 4; ++i) {
      const int m = m0 + wm + i * 16 + q * 4;
      uint2 p;
      p.x = pack2(acc[i][j][0] + bv, acc[i][j][1] + bv);
      p.y = pack2(acc[i][j][2] + bv, acc[i][j][3] + bv);
      *(uint2*)&HT[(size_t)n * 16384 + m] = p;
    }
  }
}

// ---------------- Kernel 2: out[m][n] += A_hat[m][k] H[k][n] --------------------
__global__ __launch_bounds__(512, 2)
void gcn_agg(const float* __restrict__ A, const unsigned short* __restrict__ HT,
             float* __restrict__ out) {
  __shared__ unsigned short Asm[128 * 40];
  __shared__ unsigned short Bsm[256 * 40];
  const int tid = threadIdx.x;
  const int bx = blockIdx.x;
  const int m0 = (bx & 127) * 128;     // 128 m-tiles
  const int kb = (bx >> 7) * 8192;     // 2 K-chunks
  const int lane = tid & 63;
  const int w = tid >> 6;              // 8 waves: 2(m) x 4(n), each 64x64
  const int wm = (w & 1) * 64;
  const int wn = (w >> 1) * 64;
  const int ln = lane & 15;
  const int q = lane >> 4;

  f32x4 acc[4][4];
#pragma unroll
  for (int i = 0; i < 4; ++i)
#pragma unroll
    for (int j = 0; j < 4; ++j) acc[i][j] = (f32x4)0.0f;

  const int ar = tid >> 2;            // 0..127 A tile row
  const int ac = (tid & 3) * 4;       // col base {0,4,8,12}; also +16
  const int bn = tid >> 1;            // 0..255 B tile row (n)
  const int bc = (tid & 1) * 8;       // col base {0,8}; also +16

  const float* ap = A + (size_t)(m0 + ar) * 16384 + ac;
  const unsigned short* bp = HT + (size_t)bn * 16384 + bc;

  // prologue: stage tile 0
  float4 a0 = *(const float4*)(ap + kb);
  float4 a1 = *(const float4*)(ap + kb + 16);
  uint4 b0 = *(const uint4*)(bp + kb);
  uint4 b1 = *(const uint4*)(bp + kb + 16);
  {
    unsigned* ad0 = (unsigned*)&Asm[ar * 40 + ac];
    ad0[0] = pack2(a0.x, a0.y); ad0[1] = pack2(a0.z, a0.w);
    unsigned* ad1 = (unsigned*)&Asm[ar * 40 + ac + 16];
    ad1[0] = pack2(a1.x, a1.y); ad1[1] = pack2(a1.z, a1.w);
    *(uint4*)&Bsm[bn * 40 + bc] = b0;
    *(uint4*)&Bsm[bn * 40 + bc + 16] = b1;
  }
  __syncthreads();

  for (int s = 0; s < 256; ++s) {
    const bool more = (s + 1) < 256;
    float4 na0, na1; uint4 nb0, nb1;
    if (more) {  // issue next tile's global loads early (overlap with MFMA)
      const int kn = kb + (s + 1) * 32;
      na0 = *(const float4*)(ap + kn);
      na1 = *(const float4*)(ap + kn + 16);
      nb0 = *(const uint4*)(bp + kn);
      nb1 = *(const uint4*)(bp + kn + 16);
    }
    bf16x8 af[4], bfr[4];
#pragma unroll
    for (int i = 0; i < 4; ++i)
      af[i] = *(const bf16x8*)&Asm[(wm + i * 16 + ln) * 40 + q * 8];
#pragma unroll
    for (int j = 0; j < 4; ++j)
      bfr[j] = *(const bf16x8*)&Bsm[(wn + j * 16 + ln) * 40 + q * 8];
#pragma unroll
    for (int i = 0; i < 4; ++i)
#pragma unroll
      for (int j = 0; j < 4; ++j)
        acc[i][j] = __builtin_amdgcn_mfma_f32_16x16x32_bf16(af[i], bfr[j], acc[i][j], 0, 0, 0);
    __syncthreads();  // all waves done reading LDS
    if (more) {
      unsigned* ad0 = (unsigned*)&Asm[ar * 40 + ac];
      ad0[0] = pack2(na0.x, na0.y); ad0[1] = pack2(na0.z, na0.w);
      unsigned* ad1 = (unsigned*)&Asm[ar * 40 + ac + 16];
      ad1[0] = pack2(na1.x, na1.y); ad1[1] = pack2(na1.z, na1.w);
      *(uint4*)&Bsm[bn * 40 + bc] = nb0;
      *(uint4*)&Bsm[bn * 40 + bc + 16] = nb1;
      __syncthreads();  // LDS ready for next compute
    }
  }

  // epilogue: split-K partial -> atomic add into zeroed d_out
#pragma unroll
  for (int i = 0; i < 4; ++i) {
    const int m = m0 + wm + i * 16 + q * 4;
#pragma unroll
    for (int j = 0; j < 4; ++j) {
      const int n = wn + j * 16 + ln;
      float* op = out + (size_t)m * 256 + n;
      atomicAdd(op + 0 * 256, acc[i][j][0]);
      atomicAdd(op + 1 * 256, acc[i][j][1]);
      atomicAdd(op + 2 * 256, acc[i][j][2]);
      atomicAdd(op + 3 * 256, acc[i][j][3]);
    }
  }
}

extern "C" void kernel_launch(void* const* d_in, const int* in_sizes, int n_in,
                              void* d_out, int out_size, void* d_ws, size_t ws_size,
                              hipStream_t stream) {
  (void)in_sizes; (void)n_in; (void)ws_size;
  const float* X = (const float*)d_in[0];
  const float* A = (const float*)d_in[1];
  const float* W = (const float*)d_in[2];
  const float* b = (const float*)d_in[3];
  float* out = (float*)d_out;
  unsigned short* HT = (unsigned short*)d_ws;  // 256*16384 bf16 = 8 MB

  hipMemsetAsync(d_out, 0, (size_t)out_size * sizeof(float), stream);
  gcn_proj<<<dim3(256), dim3(256), 0, stream>>>(X, W, b, HT);
  gcn_agg<<<dim3(256), dim3(512), 0, stream>>>(A, HT, out);
}